// Round 10
// baseline (302.766 us; speedup 1.0000x reference)
//
#include <hip/hip_runtime.h>
#include <stdint.h>

typedef unsigned short u16;
typedef __attribute__((ext_vector_type(8))) __bf16 bf16x8;
typedef __attribute__((ext_vector_type(4))) float f32x4;

__device__ __forceinline__ u16 f2bf(float f) {
  union { float f; uint32_t u; } v; v.f = f;
  uint32_t u = v.u;
  uint32_t r = (u + 0x7fffu + ((u >> 16) & 1u)) >> 16;  // RNE
  return (u16)r;
}
__device__ __forceinline__ float bf2f(u16 h) {
  union { uint32_t u; float f; } v; v.u = ((uint32_t)h) << 16;
  return v.f;
}

// async 16B/lane global->LDS. LDS dest = wave-uniform base + lane*16 (m104).
__device__ __forceinline__ void gld16(const void* g, void* l) {
  __builtin_amdgcn_global_load_lds(
      (__attribute__((address_space(1))) void*)(uintptr_t)g,
      (__attribute__((address_space(3))) void*)l,
      16, 0, 0);
}

// ---------------- fused fp32 -> bf16 cast of all 5 inputs (grid-stride) ----------------
__global__ __launch_bounds__(256) void cast_all(const float* __restrict__ x,
                                                const float* __restrict__ wq,
                                                const float* __restrict__ wk,
                                                const float* __restrict__ wv,
                                                const float* __restrict__ wo,
                                                u16* __restrict__ xb,
                                                u16* __restrict__ wqkv,
                                                u16* __restrict__ wob) {
  // total float4 elements: x 2097152 | wq 1048576 | wk 262144 | wv 262144 | wo 1048576
  for (int i = blockIdx.x * 256 + threadIdx.x; i < 4718592; i += 2048 * 256) {
    const float* src; u16* dst; int loc, base;
    if (i < 2097152)      { src = x;  dst = xb;   loc = i;           base = 0; }
    else if (i < 3145728) { src = wq; dst = wqkv; loc = i - 2097152; base = 0; }
    else if (i < 3407872) { src = wk; dst = wqkv; loc = i - 3145728; base = 1048576; }
    else if (i < 3670016) { src = wv; dst = wqkv; loc = i - 3407872; base = 1310720; }
    else                  { src = wo; dst = wob;  loc = i - 3670016; base = 0; }
    float4 f = ((const float4*)src)[loc];
    ushort4 o;
    o.x = f2bf(f.x); o.y = f2bf(f.y); o.z = f2bf(f.z); o.w = f2bf(f.w);
    ((ushort4*)dst)[base + loc] = o;
  }
}

// ---------------- bf16 GEMM, C = A * B^T, double-buffered LDS ----------------
// Issue-early/drain-late (validated on the output GEMM in R7): ONE
// __syncthreads per K-tile; stage(t+1) into the alternate buffer right after
// the barrier, compute(t). The barrier's vmcnt(0) retires loads that had a
// full compute phase in flight -> cheap.
// Epilogues (wave/block-uniform flags): do_rope -> cols<2560 fused RoPE (q
// also scaled log2e/sqrt128), v-cols (>=2560) written TRANSPOSED to Vtg[d][s];
// out_f32 -> f32 C store (output GEMM). T1 XCD-contiguous swizzle.
__global__ __launch_bounds__(256) void gemm_bt_dbuf(const u16* __restrict__ A,
                                                    const u16* __restrict__ B,
                                                    void* __restrict__ C,
                                                    u16* __restrict__ Vtg,
                                                    int M, int N, int K,
                                                    int out_f32, int do_rope)
{
  __shared__ u16 As[2][128 * 64];
  __shared__ u16 Bs[2][128 * 64];
  const int tid  = threadIdx.x;
  const int wave = tid >> 6, lane = tid & 63;
  const int col  = lane & 15, quad = lane >> 4;

  // T1: XCD-contiguous work remap (grids here are %8==0; guarded fallback).
  const int nwg = gridDim.x * gridDim.y;
  int flat = blockIdx.y * gridDim.x + blockIdx.x;
  int swz  = (nwg & 7) ? flat : ((flat & 7) * (nwg >> 3) + (flat >> 3));
  const int bm = swz / gridDim.x, bn = swz % gridDim.x;

  const int wm = (wave >> 1) * 64, wn = (wave & 1) * 64;
  const size_t arow0 = (size_t)bm * 128, brow0 = (size_t)bn * 128;
  const int sr = lane >> 3, pc = lane & 7;

  const f32x4 fz = {0.f, 0.f, 0.f, 0.f};
  f32x4 acc[4][4];
  for (int i = 0; i < 4; ++i)
    for (int j = 0; j < 4; ++j) acc[i][j] = fz;

  // prologue: stage tile 0 into buf 0
  #pragma unroll
  for (int i = 0; i < 4; ++i) {
    int rA = wave * 32 + i * 8 + sr;
    int lc = pc ^ (rA & 7);
    gld16(A + (arow0 + rA) * K + lc * 8, As[0] + (wave * 32 + i * 8) * 64);
    gld16(B + (brow0 + rA) * K + lc * 8, Bs[0] + (wave * 32 + i * 8) * 64);
  }

  const int T = K / 64;
  for (int t = 0; t < T; ++t) {
    __syncthreads();   // drains stage(t) (issued one iter ago; covered by compute)
    if (t + 1 < T) {
      const int k0 = (t + 1) * 64;
      u16* ad = As[(t + 1) & 1];
      u16* bd = Bs[(t + 1) & 1];
      #pragma unroll
      for (int i = 0; i < 4; ++i) {
        int rA = wave * 32 + i * 8 + sr;
        int lc = pc ^ (rA & 7);
        gld16(A + (arow0 + rA) * K + k0 + lc * 8, ad + (wave * 32 + i * 8) * 64);
        gld16(B + (brow0 + rA) * K + k0 + lc * 8, bd + (wave * 32 + i * 8) * 64);
      }
    }
    const u16* Ac = As[t & 1];
    const u16* Bc = Bs[t & 1];
    #pragma unroll
    for (int kk = 0; kk < 2; ++kk) {
      const int swzk = (((kk * 4 + quad) ^ (col & 7)) * 8);
      bf16x8 af[4];
      #pragma unroll
      for (int mt = 0; mt < 4; ++mt)
        af[mt] = *(const bf16x8*)&Ac[(wm + mt * 16 + col) * 64 + swzk];
      #pragma unroll
      for (int nt = 0; nt < 4; ++nt) {
        bf16x8 bf = *(const bf16x8*)&Bc[(wn + nt * 16 + col) * 64 + swzk];
        #pragma unroll
        for (int mt = 0; mt < 4; ++mt)
          acc[mt][nt] = __builtin_amdgcn_mfma_f32_16x16x32_bf16(af[mt], bf, acc[mt][nt], 0, 0, 0);
      }
    }
  }

  // epilogue (+ optional fused RoPE / transposed-V write)
  const float qscale = 0.12751744515623627f;  // log2(e)/sqrt(128)
  #pragma unroll
  for (int mt = 0; mt < 4; ++mt)
    #pragma unroll
    for (int nt = 0; nt < 4; ++nt) {
      const size_t gcol = brow0 + wn + nt * 16 + col;
      // wave-uniform: 16-col group entirely inside one region
      const bool v_here    = do_rope && (gcol >= 2560);
      const bool rope_here = do_rope && (gcol < 2560);
      const int  d    = (int)(gcol & 127);
      const float osc = (gcol < 2048) ? qscale : 1.0f;
      const float inv = exp2f(-(float)(d >> 1) * 0.20762050593046f);  // 10000^(-2i/128)
      const bool odd  = (d & 1) != 0;
      if (v_here) {
        // transposed V write: 4 consecutive token positions s -> one ushort4
        const int vc  = (int)gcol - 2560;
        const int kvh = vc >> 7;
        const size_t grow0 = arow0 + wm + mt * 16 + quad * 4;   // b*2048 + s0
        const int bb = (int)(grow0 >> 11);
        const int s0 = (int)(grow0 & 2047);
        ushort4 o4;
        o4.x = f2bf(acc[mt][nt][0]);
        o4.y = f2bf(acc[mt][nt][1]);
        o4.z = f2bf(acc[mt][nt][2]);
        o4.w = f2bf(acc[mt][nt][3]);
        *(ushort4*)&Vtg[((size_t)((bb * 4 + kvh) * 128 + d)) * 2048 + s0] = o4;
        continue;
      }
      #pragma unroll
      for (int i = 0; i < 4; ++i) {
        size_t grow = arow0 + wm + mt * 16 + quad * 4 + i;
        float v = acc[mt][nt][i];
        if (rope_here) {
          float p = __shfl_xor(v, 1);            // partner column d^1
          float ang = (float)(int)(grow & 2047) * inv;  // s = token pos (S=2048)
          float sn, cs;
          __sincosf(ang, &sn, &cs);
          v = odd ? (p * sn + v * cs) * osc : (v * cs - p * sn) * osc;
        }
        if (out_f32) ((float*)C)[grow * N + gcol] = v;
        else         ((u16*)C)[grow * N + gcol]   = f2bf(v);
      }
    }
}

// ---------------- causal flash attention, GQA 4:1, no-max softmax ----------------
// (round-9 verbatim: 2-barrier loop, 8 waves x 16 q-rows, 512 threads --
// counter-validated: 74.5us, MfmaUtil 18.9, occupancy 25.8%)
__global__ __launch_bounds__(512, 4) void attn_kernel(const u16* __restrict__ QKV,
                                                      const u16* __restrict__ Vtg,
                                                      u16* __restrict__ Ctx,
                                                      int B, int S)
{
  const int x = blockIdx.x;                 // 512 blocks
  const int t = x >> 5, bh = x & 31;
  const int qt = (x < 256) ? (15 - t) : (t - 8);   // heavy first; pairs (c,c+256) sum 15
  const int h = bh & 15, b = bh >> 4;
  const int tid  = threadIdx.x;
  const int wave = tid >> 6, lane = tid & 63;     // wave 0..7
  const int col  = lane & 15, quad = lane >> 4;
  const int q0   = qt * 128;
  const int kvh  = h >> 2;
  const int row0w = q0 + wave * 16;               // 16 q-rows per wave

  __shared__ u16 Ks[64 * 128];    // [key][d], 16B chunks phys = c ^ (key&15)
  __shared__ u16 Vt[128 * 64];    // [d][key], 16B chunks phys = c ^ (d&7)
  __shared__ u16 Ps[8][16 * 72];  // per-wave P: [qrow][key], stride 72

  // Q B-operand frags (scale log2e/sqrt(128) pre-folded in rope)
  bf16x8 aq[4];
  #pragma unroll
  for (int ks = 0; ks < 4; ++ks)
    aq[ks] = *(const bf16x8*)(QKV + (size_t)(b * S + row0w + col) * 3072
                                  + h * 128 + ks * 32 + quad * 8);

  const u16* KVb = QKV + (size_t)b * S * 3072 + 2048 + kvh * 128;
  const u16* Vtb = Vtg + ((size_t)(b * 4 + kvh) * 128) * S;
  u16* Pw = Ps[wave];

  const f32x4 fz = {0.f, 0.f, 0.f, 0.f};
  f32x4 o[8];
  #pragma unroll
  for (int nc = 0; nc < 8; ++nc) o[nc] = fz;
  float rs = 0.f;   // per-lane: qrow = row0w + col

  const int kt_max = 2 * qt + 1;

  for (int kt = 0; kt <= kt_max; ++kt) {
    __syncthreads();   // prior tile reads done
    // stage K: 64 rows x 256B; per wave 2 issues x 4 rows
    #pragma unroll
    for (int i = 0; i < 2; ++i) {
      int r = wave * 8 + i * 4 + (lane >> 4);
      int lc = (lane & 15) ^ (r & 15);
      gld16(KVb + (size_t)(kt * 64 + r) * 3072 + lc * 8, Ks + (wave * 8 + i * 4) * 128);
    }
    // stage V^T: 128 rows x 128B; per wave 2 issues x 8 rows
    #pragma unroll
    for (int i = 0; i < 2; ++i) {
      int r = wave * 16 + i * 8 + (lane >> 3);
      int lc = (lane & 7) ^ (r & 7);
      gld16(Vtb + (size_t)r * S + kt * 64 + lc * 8, Vt + (wave * 16 + i * 8) * 64);
    }
    __syncthreads();   // drain -> staged data visible

    if (kt * 64 > row0w + 15) continue;   // wave fully masked (uniform; barriers above)
    const bool need_mask = (kt * 64 + 63 > row0w);

    // S^T = K Q^T per 16-key group; write P[qrow][key] as b64
    #pragma unroll
    for (int nt = 0; nt < 4; ++nt) {
      bf16x8 kA[4];
      #pragma unroll
      for (int ks = 0; ks < 4; ++ks)
        kA[ks] = *(const bf16x8*)&Ks[(nt * 16 + col) * 128 + (((ks * 4 + quad) ^ col) * 8)];
      f32x4 st = fz;
      #pragma unroll
      for (int ks = 0; ks < 4; ++ks)
        st = __builtin_amdgcn_mfma_f32_16x16x32_bf16(kA[ks], aq[ks], st, 0, 0, 0);
      // lane: key = kt*64 + nt*16 + quad*4 + i, qrow = row0w + col
      float pv[4];
      const int kbase = kt * 64 + nt * 16 + quad * 4;
      const int qrow  = row0w + col;
      #pragma unroll
      for (int i = 0; i < 4; ++i) {
        float s = st[i];
        if (need_mask && (kbase + i > qrow)) s = -__builtin_inff();
        pv[i] = exp2f(s);
      }
      rs += (pv[0] + pv[1]) + (pv[2] + pv[3]);
      uint32_t d0 = (__float_as_uint(pv[0]) >> 16) | (__float_as_uint(pv[1]) & 0xffff0000u);
      uint32_t d1 = (__float_as_uint(pv[2]) >> 16) | (__float_as_uint(pv[3]) & 0xffff0000u);
      uint2 dd; dd.x = d0; dd.y = d1;
      *(uint2*)&Pw[col * 72 + nt * 16 + quad * 4] = dd;
    }
    __asm__ volatile("" ::: "memory");

    // PV: P A-frags (b128), V^T B-frags
    bf16x8 ap[2];
    #pragma unroll
    for (int ks = 0; ks < 2; ++ks)
      ap[ks] = *(const bf16x8*)&Pw[col * 72 + ks * 32 + quad * 8];
    #pragma unroll
    for (int nc = 0; nc < 8; ++nc) {
      #pragma unroll
      for (int ks = 0; ks < 2; ++ks) {
        bf16x8 bv = *(const bf16x8*)&Vt[(nc * 16 + col) * 64 + (((ks * 4 + quad) ^ (col & 7)) * 8)];
        o[nc] = __builtin_amdgcn_mfma_f32_16x16x32_bf16(ap[ks], bv, o[nc], 0, 0, 0);
      }
    }
  }

  // epilogue: reduce rs over the 4 quad-copies, normalize, store
  {
    float v = rs;
    v += __shfl_xor(v, 16);
    v += __shfl_xor(v, 32);
    float lv[4];
    #pragma unroll
    for (int i = 0; i < 4; ++i)
      lv[i] = 1.0f / __shfl(v, quad * 4 + i);
    #pragma unroll
    for (int nc = 0; nc < 8; ++nc)
      #pragma unroll
      for (int i = 0; i < 4; ++i) {
        int qg = row0w + quad * 4 + i;
        Ctx[(size_t)(b * S + qg) * 2048 + h * 128 + nc * 16 + col] =
            f2bf(o[nc][i] * lv[i]);
      }
  }
}

extern "C" void kernel_launch(void* const* d_in, const int* in_sizes, int n_in,
                              void* d_out, int out_size, void* d_ws, size_t ws_size,
                              hipStream_t stream) {
  const int B = 2, S = 2048, D = 2048;
  const int M = B * S;            // 4096
  const int NQKV = 3072;          // q 0..2047 | k 2048..2559 | v 2560..3071 (v -> Vtg only)

  const float* x  = (const float*)d_in[0];
  const float* wq = (const float*)d_in[1];
  const float* wk = (const float*)d_in[2];
  const float* wv = (const float*)d_in[3];
  const float* wo = (const float*)d_in[4];

  char* ws = (char*)d_ws;
  u16* xb    = (u16*)ws; ws += (size_t)M * D * 2;
  u16* wqkvb = (u16*)ws; ws += (size_t)NQKV * D * 2;
  u16* wob   = (u16*)ws; ws += (size_t)D * D * 2;
  u16* qkvb  = (u16*)ws; ws += (size_t)M * NQKV * 2;
  u16* vtg   = (u16*)ws; ws += (size_t)B * 4 * 128 * S * 2;
  u16* ctx   = (u16*)ws; ws += (size_t)M * D * 2;

  cast_all<<<2048, 256, 0, stream>>>(x, wq, wk, wv, wo, xb, wqkvb, wob);

  // QKV GEMM (dbuf) with fused RoPE epilogue + transposed-V write
  gemm_bt_dbuf<<<dim3(NQKV / 128, M / 128), 256, 0, stream>>>(
      xb, wqkvb, qkvb, vtg, M, NQKV, D, 0, 1);

  attn_kernel<<<512, 512, 0, stream>>>(qkvb, vtg, ctx, B, S);

  // output GEMM (dbuf), f32 out
  gemm_bt_dbuf<<<dim3(D / 128, M / 128), 256, 0, stream>>>(
      ctx, wob, d_out, nullptr, M, D, D, 1, 0);
}

// Round 11
// 281.107 us; speedup vs baseline: 1.0770x; 1.0770x over previous
//
#include <hip/hip_runtime.h>
#include <stdint.h>

typedef unsigned short u16;
typedef __attribute__((ext_vector_type(8))) __bf16 bf16x8;
typedef __attribute__((ext_vector_type(4))) float f32x4;

__device__ __forceinline__ u16 f2bf(float f) {
  union { float f; uint32_t u; } v; v.f = f;
  uint32_t u = v.u;
  uint32_t r = (u + 0x7fffu + ((u >> 16) & 1u)) >> 16;  // RNE
  return (u16)r;
}
__device__ __forceinline__ float bf2f(u16 h) {
  union { uint32_t u; float f; } v; v.u = ((uint32_t)h) << 16;
  return v.f;
}

// async 16B/lane global->LDS. LDS dest = wave-uniform base + lane*16 (m104).
__device__ __forceinline__ void gld16(const void* g, void* l) {
  __builtin_amdgcn_global_load_lds(
      (__attribute__((address_space(1))) void*)(uintptr_t)g,
      (__attribute__((address_space(3))) void*)l,
      16, 0, 0);
}

// T1 + L2 super-tiling: XCD x owns bm-rows [x*4, x*4+4); within the chunk,
// iterate 4bm x 4bn super-tiles (A-slab 2MB + B-slab 2MB = 4MB = L2/XCD).
// Bijective for gridDim.y==32, gridDim.x%4==0 (both GEMM grids). Fallback: linear.
__device__ __forceinline__ void xcd_supertile(int& bm, int& bn) {
  int flat = blockIdx.y * gridDim.x + blockIdx.x;
  if (gridDim.y == 32 && (gridDim.x & 3) == 0) {
    int xcd = flat & 7;
    int c   = flat >> 3;          // [0, gridDim.x*4)
    int st  = c >> 4;             // supertile along bn: [0, gridDim.x/4)
    int r   = c & 15;             // 16 blocks per 4x4 supertile
    bm = xcd * 4 + (r >> 2);
    bn = st * 4 + (r & 3);
  } else {
    bm = flat / gridDim.x;
    bn = flat % gridDim.x;
  }
}

// ---------------- fused fp32 -> bf16 cast of all 5 inputs (grid-stride) ----------------
__global__ __launch_bounds__(256) void cast_all(const float* __restrict__ x,
                                                const float* __restrict__ wq,
                                                const float* __restrict__ wk,
                                                const float* __restrict__ wv,
                                                const float* __restrict__ wo,
                                                u16* __restrict__ xb,
                                                u16* __restrict__ wqkv,
                                                u16* __restrict__ wob) {
  // total float4 elements: x 2097152 | wq 1048576 | wk 262144 | wv 262144 | wo 1048576
  for (int i = blockIdx.x * 256 + threadIdx.x; i < 4718592; i += 2048 * 256) {
    const float* src; u16* dst; int loc, base;
    if (i < 2097152)      { src = x;  dst = xb;   loc = i;           base = 0; }
    else if (i < 3145728) { src = wq; dst = wqkv; loc = i - 2097152; base = 0; }
    else if (i < 3407872) { src = wk; dst = wqkv; loc = i - 3145728; base = 1048576; }
    else if (i < 3670016) { src = wv; dst = wqkv; loc = i - 3407872; base = 1310720; }
    else                  { src = wo; dst = wob;  loc = i - 3670016; base = 0; }
    float4 f = ((const float4*)src)[loc];
    ushort4 o;
    o.x = f2bf(f.x); o.y = f2bf(f.y); o.z = f2bf(f.z); o.w = f2bf(f.w);
    ((ushort4*)dst)[base + loc] = o;
  }
}

// ---------------- bf16 GEMM, C = A * B^T  (BK=64, m97-style 2-barrier staging) ----
// 32KB LDS -> 3 blocks/CU (the drain is hidden by the 3rd co-resident block;
// dbuf conversion measured WORSE here, R10). do_rope: cols<2560 fused RoPE
// (q also scaled log2e/sqrt128); v-cols (>=2560) written TRANSPOSED to
// Vtg[d][s]. L2 super-tiled XCD swizzle.
__global__ __launch_bounds__(256) void gemm_bt(const u16* __restrict__ A,
                                               const u16* __restrict__ B,
                                               void* __restrict__ C,
                                               u16* __restrict__ Vtg,
                                               int M, int N, int K, int out_f32,
                                               int do_rope)
{
  __shared__ u16 As[128 * 64];
  __shared__ u16 Bs[128 * 64];
  const int tid  = threadIdx.x;
  const int wave = tid >> 6, lane = tid & 63;
  const int col  = lane & 15, quad = lane >> 4;

  int bm, bn;
  xcd_supertile(bm, bn);

  const int wm = (wave >> 1) * 64, wn = (wave & 1) * 64;
  const size_t arow0 = (size_t)bm * 128, brow0 = (size_t)bn * 128;

  const int sr = lane >> 3, pc = lane & 7;

  const f32x4 fz = {0.f, 0.f, 0.f, 0.f};
  f32x4 acc[4][4];
  for (int i = 0; i < 4; ++i)
    for (int j = 0; j < 4; ++j) acc[i][j] = fz;

  for (int k0 = 0; k0 < K; k0 += 64) {
    __syncthreads();
    #pragma unroll
    for (int i = 0; i < 4; ++i) {
      int rA = wave * 32 + i * 8 + sr;
      int lc = pc ^ (rA & 7);
      gld16(A + (arow0 + rA) * K + k0 + lc * 8, As + (wave * 32 + i * 8) * 64);
      gld16(B + (brow0 + rA) * K + k0 + lc * 8, Bs + (wave * 32 + i * 8) * 64);
    }
    __syncthreads();
    #pragma unroll
    for (int kk = 0; kk < 2; ++kk) {
      const int swzk = (((kk * 4 + quad) ^ (col & 7)) * 8);
      bf16x8 af[4];
      #pragma unroll
      for (int mt = 0; mt < 4; ++mt)
        af[mt] = *(const bf16x8*)&As[(wm + mt * 16 + col) * 64 + swzk];
      #pragma unroll
      for (int nt = 0; nt < 4; ++nt) {
        bf16x8 bf = *(const bf16x8*)&Bs[(wn + nt * 16 + col) * 64 + swzk];
        #pragma unroll
        for (int mt = 0; mt < 4; ++mt)
          acc[mt][nt] = __builtin_amdgcn_mfma_f32_16x16x32_bf16(af[mt], bf, acc[mt][nt], 0, 0, 0);
      }
    }
  }

  // epilogue (+ optional fused RoPE / transposed-V write)
  const float qscale = 0.12751744515623627f;  // log2(e)/sqrt(128)
  #pragma unroll
  for (int mt = 0; mt < 4; ++mt)
    #pragma unroll
    for (int nt = 0; nt < 4; ++nt) {
      const size_t gcol = brow0 + wn + nt * 16 + col;
      // wave-uniform: 16-col group entirely inside one region
      const bool v_here    = do_rope && (gcol >= 2560);
      const bool rope_here = do_rope && (gcol < 2560);
      const int  d    = (int)(gcol & 127);
      const float osc = (gcol < 2048) ? qscale : 1.0f;
      const float inv = exp2f(-(float)(d >> 1) * 0.20762050593046f);  // 10000^(-2i/128)
      const bool odd  = (d & 1) != 0;
      if (v_here) {
        // transposed V write: 4 consecutive token positions s -> one ushort4
        const int vc  = (int)gcol - 2560;
        const int kvh = vc >> 7;
        const size_t grow0 = arow0 + wm + mt * 16 + quad * 4;   // b*2048 + s0
        const int bb = (int)(grow0 >> 11);
        const int s0 = (int)(grow0 & 2047);
        ushort4 o4;
        o4.x = f2bf(acc[mt][nt][0]);
        o4.y = f2bf(acc[mt][nt][1]);
        o4.z = f2bf(acc[mt][nt][2]);
        o4.w = f2bf(acc[mt][nt][3]);
        *(ushort4*)&Vtg[((size_t)((bb * 4 + kvh) * 128 + d)) * 2048 + s0] = o4;
        continue;
      }
      #pragma unroll
      for (int i = 0; i < 4; ++i) {
        size_t grow = arow0 + wm + mt * 16 + quad * 4 + i;
        float v = acc[mt][nt][i];
        if (rope_here) {
          float p = __shfl_xor(v, 1);            // partner column d^1
          float ang = (float)(int)(grow & 2047) * inv;  // s = token pos (S=2048)
          float sn, cs;
          __sincosf(ang, &sn, &cs);
          v = odd ? (p * sn + v * cs) * osc : (v * cs - p * sn) * osc;
        }
        if (out_f32) ((float*)C)[grow * N + gcol] = v;
        else         ((u16*)C)[grow * N + gcol]   = f2bf(v);
      }
    }
}

// ---------------- bf16 GEMM, double-buffered LDS (issue-early / drain-late) ----
// (R7-validated for the output GEMM: 2 blocks/CU regime where the drain is
// otherwise exposed.) f32 output. L2 super-tiled XCD swizzle.
__global__ __launch_bounds__(256) void gemm_bt_dbuf(const u16* __restrict__ A,
                                                    const u16* __restrict__ B,
                                                    float* __restrict__ C,
                                                    int M, int N, int K)
{
  __shared__ u16 As[2][128 * 64];
  __shared__ u16 Bs[2][128 * 64];
  const int tid  = threadIdx.x;
  const int wave = tid >> 6, lane = tid & 63;
  const int col  = lane & 15, quad = lane >> 4;

  int bm, bn;
  xcd_supertile(bm, bn);

  const int wm = (wave >> 1) * 64, wn = (wave & 1) * 64;
  const size_t arow0 = (size_t)bm * 128, brow0 = (size_t)bn * 128;
  const int sr = lane >> 3, pc = lane & 7;

  const f32x4 fz = {0.f, 0.f, 0.f, 0.f};
  f32x4 acc[4][4];
  for (int i = 0; i < 4; ++i)
    for (int j = 0; j < 4; ++j) acc[i][j] = fz;

  #pragma unroll
  for (int i = 0; i < 4; ++i) {
    int rA = wave * 32 + i * 8 + sr;
    int lc = pc ^ (rA & 7);
    gld16(A + (arow0 + rA) * K + lc * 8, As[0] + (wave * 32 + i * 8) * 64);
    gld16(B + (brow0 + rA) * K + lc * 8, Bs[0] + (wave * 32 + i * 8) * 64);
  }

  const int T = K / 64;
  for (int t = 0; t < T; ++t) {
    __syncthreads();   // drains stage(t) (issued one iter ago; covered by compute)
    if (t + 1 < T) {
      const int k0 = (t + 1) * 64;
      u16* ad = As[(t + 1) & 1];
      u16* bd = Bs[(t + 1) & 1];
      #pragma unroll
      for (int i = 0; i < 4; ++i) {
        int rA = wave * 32 + i * 8 + sr;
        int lc = pc ^ (rA & 7);
        gld16(A + (arow0 + rA) * K + k0 + lc * 8, ad + (wave * 32 + i * 8) * 64);
        gld16(B + (brow0 + rA) * K + k0 + lc * 8, bd + (wave * 32 + i * 8) * 64);
      }
    }
    const u16* Ac = As[t & 1];
    const u16* Bc = Bs[t & 1];
    #pragma unroll
    for (int kk = 0; kk < 2; ++kk) {
      const int swzk = (((kk * 4 + quad) ^ (col & 7)) * 8);
      bf16x8 af[4];
      #pragma unroll
      for (int mt = 0; mt < 4; ++mt)
        af[mt] = *(const bf16x8*)&Ac[(wm + mt * 16 + col) * 64 + swzk];
      #pragma unroll
      for (int nt = 0; nt < 4; ++nt) {
        bf16x8 bf = *(const bf16x8*)&Bc[(wn + nt * 16 + col) * 64 + swzk];
        #pragma unroll
        for (int mt = 0; mt < 4; ++mt)
          acc[mt][nt] = __builtin_amdgcn_mfma_f32_16x16x32_bf16(af[mt], bf, acc[mt][nt], 0, 0, 0);
      }
    }
  }

  #pragma unroll
  for (int mt = 0; mt < 4; ++mt)
    #pragma unroll
    for (int nt = 0; nt < 4; ++nt)
      #pragma unroll
      for (int i = 0; i < 4; ++i) {
        size_t grow = arow0 + wm + mt * 16 + quad * 4 + i;
        size_t gcol = brow0 + wn + nt * 16 + col;
        C[grow * N + gcol] = acc[mt][nt][i];
      }
}

// ---------------- causal flash attention, GQA 4:1, no-max softmax ----------------
// (round-9 verbatim: 2-barrier loop, 8 waves x 16 q-rows, 512 threads --
// counter-validated: 74.5us, MfmaUtil 18.9, occupancy 25.8%)
__global__ __launch_bounds__(512, 4) void attn_kernel(const u16* __restrict__ QKV,
                                                      const u16* __restrict__ Vtg,
                                                      u16* __restrict__ Ctx,
                                                      int B, int S)
{
  const int x = blockIdx.x;                 // 512 blocks
  const int t = x >> 5, bh = x & 31;
  const int qt = (x < 256) ? (15 - t) : (t - 8);   // heavy first; pairs (c,c+256) sum 15
  const int h = bh & 15, b = bh >> 4;
  const int tid  = threadIdx.x;
  const int wave = tid >> 6, lane = tid & 63;     // wave 0..7
  const int col  = lane & 15, quad = lane >> 4;
  const int q0   = qt * 128;
  const int kvh  = h >> 2;
  const int row0w = q0 + wave * 16;               // 16 q-rows per wave

  __shared__ u16 Ks[64 * 128];    // [key][d], 16B chunks phys = c ^ (key&15)
  __shared__ u16 Vt[128 * 64];    // [d][key], 16B chunks phys = c ^ (d&7)
  __shared__ u16 Ps[8][16 * 72];  // per-wave P: [qrow][key], stride 72

  // Q B-operand frags (scale log2e/sqrt(128) pre-folded in rope)
  bf16x8 aq[4];
  #pragma unroll
  for (int ks = 0; ks < 4; ++ks)
    aq[ks] = *(const bf16x8*)(QKV + (size_t)(b * S + row0w + col) * 3072
                                  + h * 128 + ks * 32 + quad * 8);

  const u16* KVb = QKV + (size_t)b * S * 3072 + 2048 + kvh * 128;
  const u16* Vtb = Vtg + ((size_t)(b * 4 + kvh) * 128) * S;
  u16* Pw = Ps[wave];

  const f32x4 fz = {0.f, 0.f, 0.f, 0.f};
  f32x4 o[8];
  #pragma unroll
  for (int nc = 0; nc < 8; ++nc) o[nc] = fz;
  float rs = 0.f;   // per-lane: qrow = row0w + col

  const int kt_max = 2 * qt + 1;

  for (int kt = 0; kt <= kt_max; ++kt) {
    __syncthreads();   // prior tile reads done
    // stage K: 64 rows x 256B; per wave 2 issues x 4 rows
    #pragma unroll
    for (int i = 0; i < 2; ++i) {
      int r = wave * 8 + i * 4 + (lane >> 4);
      int lc = (lane & 15) ^ (r & 15);
      gld16(KVb + (size_t)(kt * 64 + r) * 3072 + lc * 8, Ks + (wave * 8 + i * 4) * 128);
    }
    // stage V^T: 128 rows x 128B; per wave 2 issues x 8 rows
    #pragma unroll
    for (int i = 0; i < 2; ++i) {
      int r = wave * 16 + i * 8 + (lane >> 3);
      int lc = (lane & 7) ^ (r & 7);
      gld16(Vtb + (size_t)r * S + kt * 64 + lc * 8, Vt + (wave * 16 + i * 8) * 64);
    }
    __syncthreads();   // drain -> staged data visible

    if (kt * 64 > row0w + 15) continue;   // wave fully masked (uniform; barriers above)
    const bool need_mask = (kt * 64 + 63 > row0w);

    // S^T = K Q^T per 16-key group; write P[qrow][key] as b64
    #pragma unroll
    for (int nt = 0; nt < 4; ++nt) {
      bf16x8 kA[4];
      #pragma unroll
      for (int ks = 0; ks < 4; ++ks)
        kA[ks] = *(const bf16x8*)&Ks[(nt * 16 + col) * 128 + (((ks * 4 + quad) ^ col) * 8)];
      f32x4 st = fz;
      #pragma unroll
      for (int ks = 0; ks < 4; ++ks)
        st = __builtin_amdgcn_mfma_f32_16x16x32_bf16(kA[ks], aq[ks], st, 0, 0, 0);
      // lane: key = kt*64 + nt*16 + quad*4 + i, qrow = row0w + col
      float pv[4];
      const int kbase = kt * 64 + nt * 16 + quad * 4;
      const int qrow  = row0w + col;
      #pragma unroll
      for (int i = 0; i < 4; ++i) {
        float s = st[i];
        if (need_mask && (kbase + i > qrow)) s = -__builtin_inff();
        pv[i] = exp2f(s);
      }
      rs += (pv[0] + pv[1]) + (pv[2] + pv[3]);
      uint32_t d0 = (__float_as_uint(pv[0]) >> 16) | (__float_as_uint(pv[1]) & 0xffff0000u);
      uint32_t d1 = (__float_as_uint(pv[2]) >> 16) | (__float_as_uint(pv[3]) & 0xffff0000u);
      uint2 dd; dd.x = d0; dd.y = d1;
      *(uint2*)&Pw[col * 72 + nt * 16 + quad * 4] = dd;
    }
    __asm__ volatile("" ::: "memory");

    // PV: P A-frags (b128), V^T B-frags
    bf16x8 ap[2];
    #pragma unroll
    for (int ks = 0; ks < 2; ++ks)
      ap[ks] = *(const bf16x8*)&Pw[col * 72 + ks * 32 + quad * 8];
    #pragma unroll
    for (int nc = 0; nc < 8; ++nc) {
      #pragma unroll
      for (int ks = 0; ks < 2; ++ks) {
        bf16x8 bv = *(const bf16x8*)&Vt[(nc * 16 + col) * 64 + (((ks * 4 + quad) ^ (col & 7)) * 8)];
        o[nc] = __builtin_amdgcn_mfma_f32_16x16x32_bf16(ap[ks], bv, o[nc], 0, 0, 0);
      }
    }
  }

  // epilogue: reduce rs over the 4 quad-copies, normalize, store
  {
    float v = rs;
    v += __shfl_xor(v, 16);
    v += __shfl_xor(v, 32);
    float lv[4];
    #pragma unroll
    for (int i = 0; i < 4; ++i)
      lv[i] = 1.0f / __shfl(v, quad * 4 + i);
    #pragma unroll
    for (int nc = 0; nc < 8; ++nc)
      #pragma unroll
      for (int i = 0; i < 4; ++i) {
        int qg = row0w + quad * 4 + i;
        Ctx[(size_t)(b * S + qg) * 2048 + h * 128 + nc * 16 + col] =
            f2bf(o[nc][i] * lv[i]);
      }
  }
}

extern "C" void kernel_launch(void* const* d_in, const int* in_sizes, int n_in,
                              void* d_out, int out_size, void* d_ws, size_t ws_size,
                              hipStream_t stream) {
  const int B = 2, S = 2048, D = 2048;
  const int M = B * S;            // 4096
  const int NQKV = 3072;          // q 0..2047 | k 2048..2559 | v 2560..3071 (v -> Vtg only)

  const float* x  = (const float*)d_in[0];
  const float* wq = (const float*)d_in[1];
  const float* wk = (const float*)d_in[2];
  const float* wv = (const float*)d_in[3];
  const float* wo = (const float*)d_in[4];

  char* ws = (char*)d_ws;
  u16* xb    = (u16*)ws; ws += (size_t)M * D * 2;
  u16* wqkvb = (u16*)ws; ws += (size_t)NQKV * D * 2;
  u16* wob   = (u16*)ws; ws += (size_t)D * D * 2;
  u16* qkvb  = (u16*)ws; ws += (size_t)M * NQKV * 2;
  u16* vtg   = (u16*)ws; ws += (size_t)B * 4 * 128 * S * 2;
  u16* ctx   = (u16*)ws; ws += (size_t)M * D * 2;

  cast_all<<<2048, 256, 0, stream>>>(x, wq, wk, wv, wo, xb, wqkvb, wob);

  // QKV GEMM (2-barrier, 3 blocks/CU) with fused RoPE + transposed-V write
  gemm_bt<<<dim3(NQKV / 128, M / 128), 256, 0, stream>>>(xb, wqkvb, qkvb, vtg, M, NQKV, D, 0, 1);

  attn_kernel<<<512, 512, 0, stream>>>(qkvb, vtg, ctx, B, S);

  // output GEMM (dbuf, 2 blocks/CU regime), f32 out
  gemm_bt_dbuf<<<dim3(D / 128, M / 128), 256, 0, stream>>>(ctx, wob, (float*)d_out, M, D, D);
}